// Round 9
// baseline (364.727 us; speedup 1.0000x reference)
//
#include <hip/hip_runtime.h>
#include <hip/hip_bf16.h>
#include <cstdint>

#define M_ROWS 131072
#define D_DIM  256
#define K_CL   512

typedef __attribute__((ext_vector_type(4))) float  f4;
typedef __attribute__((ext_vector_type(8))) short  bfrag;   // 8 bf16 (4 VGPRs)
typedef __attribute__((ext_vector_type(4))) float  ffrag;   // 4 f32 acc

#define MFMA16(A,B,C) __builtin_amdgcn_mfma_f32_16x16x32_bf16((A),(B),(C),0,0,0)

__device__ __forceinline__ ffrag fzero() {
    ffrag z;
    z[0] = 0.f; z[1] = 0.f; z[2] = 0.f; z[3] = 0.f;
    return z;
}

__device__ __forceinline__ unsigned short f2bf(float f) {
    unsigned int u = __float_as_uint(f);
    u += 0x7FFFu + ((u >> 16) & 1u);          // round-to-nearest-even
    return (unsigned short)(u >> 16);
}
__device__ __forceinline__ float bf2f(unsigned short u) {
    return __uint_as_float(((unsigned int)u) << 16);
}

// ---------------------------------------------------------------------------
// Prep: cluster_center f32 [512][256] -> Cb bf16 [512][256], Ct bf16 [256][512],
// c_sq[512] (sum of squares of the bf16-rounded values).
// ---------------------------------------------------------------------------
__global__ void prep_kernel(const float* __restrict__ C,
                            unsigned short* __restrict__ Cb,
                            unsigned short* __restrict__ Ct,
                            float* __restrict__ csq)
{
    __shared__ unsigned short lds[64 * 264];
    const int tid = threadIdx.x;          // 256 threads
    const int kb  = blockIdx.x * 64;      // 8 blocks
    const int r   = tid >> 2;
    const int q   = tid & 3;

    const float* cr = C + (size_t)(kb + r) * D_DIM;
    float s = 0.f;
    #pragma unroll
    for (int i = 0; i < 16; ++i) {
        const int j = q * 16 + i;
        f4 v = *(const f4*)(cr + j * 4);
        unsigned short u0 = f2bf(v[0]), u1 = f2bf(v[1]), u2 = f2bf(v[2]), u3 = f2bf(v[3]);
        *(ushort4*)(Cb + (size_t)(kb + r) * D_DIM + j * 4) = make_ushort4(u0, u1, u2, u3);
        *(ushort4*)(lds + r * 264 + j * 4)                  = make_ushort4(u0, u1, u2, u3);
        float f0 = bf2f(u0), f1 = bf2f(u1), f2_ = bf2f(u2), f3 = bf2f(u3);
        s += f0 * f0 + f1 * f1 + f2_ * f2_ + f3 * f3;
    }
    s += __shfl_xor(s, 1, 64);
    s += __shfl_xor(s, 2, 64);
    if (q == 0) csq[kb + r] = s;
    __syncthreads();

    #pragma unroll
    for (int c = 0; c < 16; ++c) {
        ushort4 p = make_ushort4(lds[(c * 4 + 0) * 264 + tid],
                                 lds[(c * 4 + 1) * 264 + tid],
                                 lds[(c * 4 + 2) * 264 + tid],
                                 lds[(c * 4 + 3) * 264 + tid]);
        *(ushort4*)(Ct + (size_t)tid * K_CL + kb + c * 4) = p;
    }
}

// ---------------------------------------------------------------------------
// Fused: LN -> cdist -> softmax -> x_rec. 256 thr (4 waves), 32 rows/block.
// Swapped-operand MFMA layout (verified): lane(g,cl) of wave w holds
// (row = rt*16+cl, col = w*128 + nt*16 + g*4 + r). STORES ARE SPREAD:
// out0 stored per-tile inside GEMM1; out1/out2 interleaved inside GEMM2.
// 3 barriers. Registers uncapped (R1/R8 lesson).
// ---------------------------------------------------------------------------
__global__ __launch_bounds__(256)
void fused_kernel(const float* __restrict__ x,
                  const float* __restrict__ lnw,
                  const float* __restrict__ lnb,
                  const unsigned short* __restrict__ Cb,
                  const unsigned short* __restrict__ Ct,
                  const float* __restrict__ csq,
                  float* __restrict__ out0,   // x_distance  [M][512]
                  float* __restrict__ out1,   // assign      [M][512]
                  float* __restrict__ out2)   // x_rec       [M][256]
{
    __shared__ __align__(16) char smem[34432];
    // [0, 33280): xn_s [32][264] bf16 UNION as_s [32][520] bf16
    unsigned short* xn_s = (unsigned short*)smem;
    unsigned short* as_s = (unsigned short*)smem;
    float* red_a = (float*)(smem + 33280);    // [2][4][16] f32
    float* red_b = (float*)(smem + 33792);    // [2][4][16] f32
    float* xsq_s = (float*)(smem + 34304);    // [32]

    const int tid = threadIdx.x;
    const int w   = tid >> 6;        // wave 0..3
    const int l   = tid & 63;
    const int g   = l >> 4;          // 16-lane group
    const int cl  = l & 15;
    const int m0  = blockIdx.x * 32;
    const int nb  = w * 128;         // GEMM1 col base
    const int db  = w * 64;          // GEMM2 col base

#define LOADCB(BUF, NT) {                                                       \
    const unsigned short* bp_ = Cb + (nb + (NT) * 16 + cl) * D_DIM + g * 8;     \
    _Pragma("unroll")                                                           \
    for (int i_ = 0; i_ < 8; ++i_) (BUF)[i_] = *(const bfrag*)(bp_ + i_ * 32); }

#define G1COMP(CUR, NT) {                                                       \
    ffrag a0_ = fzero(), a1_ = fzero();                                         \
    _Pragma("unroll")                                                           \
    for (int i_ = 0; i_ < 8; ++i_) {                                            \
        bfrag x0_ = *(const bfrag*)(xn_s + cl * 264 + i_ * 32 + g * 8);         \
        bfrag x1_ = *(const bfrag*)(xn_s + (16 + cl) * 264 + i_ * 32 + g * 8);  \
        a0_ = MFMA16((CUR)[i_], x0_, a0_);                                      \
        a1_ = MFMA16((CUR)[i_], x1_, a1_);                                      \
    }                                                                           \
    f4 cs_ = *(const f4*)(csq + nb + (NT) * 16 + g * 4);                        \
    f4 d0_, d1_;                                                                \
    _Pragma("unroll")                                                           \
    for (int r_ = 0; r_ < 4; ++r_) {                                            \
        d0_[r_] = sqrtf(fmaxf(xsqv0 + cs_[r_] - 2.0f * a0_[r_], 0.0f));         \
        d1_[r_] = sqrtf(fmaxf(xsqv1 + cs_[r_] - 2.0f * a1_[r_], 0.0f));         \
    }                                                                           \
    *(f4*)(out0 + (size_t)(m0 + cl) * K_CL + nb + (NT) * 16 + g * 4) = d0_;     \
    *(f4*)(out0 + (size_t)(m0 + 16 + cl) * K_CL + nb + (NT) * 16 + g * 4) = d1_;\
    dsum0 += d0_[0] + d0_[1] + d0_[2] + d0_[3];                                 \
    dsum1 += d1_[0] + d1_[1] + d1_[2] + d1_[3];                                 \
    acc[0][NT] = d0_;                                                           \
    acc[1][NT] = d1_; }

#define LOADCT(BUF, BI) {                                                       \
    const unsigned short* tp_ = Ct + (db + ((BI) >> 2) * 16 + cl) * K_CL        \
                                + ((BI) & 3) * 128 + g * 8;                     \
    _Pragma("unroll")                                                           \
    for (int i_ = 0; i_ < 4; ++i_) (BUF)[i_] = *(const bfrag*)(tp_ + i_ * 32); }

#define G2COMP(CUR, BI) {                                                       \
    _Pragma("unroll")                                                           \
    for (int i_ = 0; i_ < 4; ++i_) {                                            \
        bfrag p0_ = *(const bfrag*)(as_s + cl * 520 + ((BI) & 3) * 128 + i_ * 32 + g * 8); \
        bfrag p1_ = *(const bfrag*)(as_s + (16 + cl) * 520 + ((BI) & 3) * 128 + i_ * 32 + g * 8); \
        acc2[0][(BI) >> 2] = MFMA16((CUR)[i_], p0_, acc2[0][(BI) >> 2]);        \
        acc2[1][(BI) >> 2] = MFMA16((CUR)[i_], p1_, acc2[1][(BI) >> 2]);        \
    }                                                                           \
    {   f4 av_;                                                                 \
        _Pragma("unroll")                                                       \
        for (int r_ = 0; r_ < 4; ++r_)                                          \
            av_[r_] = acc[(BI) >> 3][(BI) & 7][r_] * rn[(BI) >> 3];             \
        *(f4*)(out1 + (size_t)(m0 + ((BI) >> 3) * 16 + cl) * K_CL               \
               + nb + ((BI) & 7) * 16 + g * 4) = av_; } }

#define G2TILE(NT) {                                                            \
    _Pragma("unroll")                                                           \
    for (int rt_ = 0; rt_ < 2; ++rt_) {                                         \
        f4 rv_;                                                                 \
        _Pragma("unroll")                                                       \
        for (int r_ = 0; r_ < 4; ++r_) rv_[r_] = acc2[rt_][NT][r_] * rn[rt_];   \
        *(f4*)(out2 + (size_t)(m0 + rt_ * 16 + cl) * D_DIM + db + (NT) * 16 + g * 4) = rv_; } }

    // ---- prefetch first Cb batch (completes under LN's HBM loads) ----
    bfrag cbA[8], cbB[8];
    LOADCB(cbA, 0);

    // ---- Phase A: LayerNorm (8 lanes per row) ----
    {
        const int rr = tid >> 3, sub = tid & 7;
        const float* xr = x + (size_t)(m0 + rr) * D_DIM;
        f4 xv[8];
        float sum = 0.f, ss = 0.f;
        #pragma unroll
        for (int i = 0; i < 8; ++i) {
            xv[i] = *(const f4*)(xr + (i * 8 + sub) * 4);
            #pragma unroll
            for (int c = 0; c < 4; ++c) { float v = xv[i][c]; sum += v; ss += v * v; }
        }
        #pragma unroll
        for (int msk = 1; msk < 8; msk <<= 1) {
            sum += __shfl_xor(sum, msk, 64);
            ss  += __shfl_xor(ss,  msk, 64);
        }
        const float mean = sum * (1.0f / 256.0f);
        float var = ss * (1.0f / 256.0f) - mean * mean;
        var = fmaxf(var, 0.0f);
        const float inv = 1.0f / (sqrtf(var) + 1e-5f);

        float xsq = 0.f;
        #pragma unroll
        for (int i = 0; i < 8; ++i) {
            f4 wv = *(const f4*)(lnw + (i * 8 + sub) * 4);
            f4 bv = *(const f4*)(lnb + (i * 8 + sub) * 4);
            float a0 = (xv[i][0] - mean) * inv * wv[0] + bv[0];
            float a1 = (xv[i][1] - mean) * inv * wv[1] + bv[1];
            float a2 = (xv[i][2] - mean) * inv * wv[2] + bv[2];
            float a3 = (xv[i][3] - mean) * inv * wv[3] + bv[3];
            unsigned short u0 = f2bf(a0), u1 = f2bf(a1), u2 = f2bf(a2), u3 = f2bf(a3);
            float c0 = bf2f(u0), c1 = bf2f(u1), c2 = bf2f(u2), c3 = bf2f(u3);
            xsq += c0 * c0 + c1 * c1 + c2 * c2 + c3 * c3;
            *(ushort4*)(xn_s + rr * 264 + (i * 8 + sub) * 4) = make_ushort4(u0, u1, u2, u3);
        }
        #pragma unroll
        for (int msk = 1; msk < 8; msk <<= 1) xsq += __shfl_xor(xsq, msk, 64);
        if (sub == 0) xsq_s[rr] = xsq;
    }
    __syncthreads();                               // barrier 1

    // ---- GEMM1 nt-major with fused distance epilogue (stores spread) ----
    const float xsqv0 = xsq_s[cl];
    const float xsqv1 = xsq_s[16 + cl];
    float dsum0 = 0.f, dsum1 = 0.f;
    ffrag acc[2][8];

    LOADCB(cbB, 1);
    G1COMP(cbA, 0); LOADCB(cbA, 2);
    G1COMP(cbB, 1); LOADCB(cbB, 3);
    G1COMP(cbA, 2); LOADCB(cbA, 4);
    G1COMP(cbB, 3); LOADCB(cbB, 5);
    G1COMP(cbA, 4); LOADCB(cbA, 6);
    G1COMP(cbB, 5); LOADCB(cbB, 7);
    G1COMP(cbA, 6);
    G1COMP(cbB, 7);

    dsum0 += __shfl_xor(dsum0, 16, 64);
    dsum0 += __shfl_xor(dsum0, 32, 64);
    dsum1 += __shfl_xor(dsum1, 16, 64);
    dsum1 += __shfl_xor(dsum1, 32, 64);
    if (l < 16) {
        red_a[w * 16 + cl]      = dsum0;
        red_a[64 + w * 16 + cl] = dsum1;
    }
    __syncthreads();                               // barrier 2

    float sc[2];
    #pragma unroll
    for (int rt = 0; rt < 2; ++rt) {
        float t = red_a[rt * 64 + cl] + red_a[rt * 64 + 16 + cl]
                + red_a[rt * 64 + 32 + cl] + red_a[rt * 64 + 48 + cl];
        sc[rt] = 16384.0f / t;                     // alpha*K/sum = 32/mean_d
    }

    // ---- prefetch first Ct batch (completes under exp phase) ----
    bfrag ctA[4], ctB[4];
    LOADCT(ctA, 0);

    // ---- Phase D: p = exp(-d*sc) (unnormalized), es partials, p->as_s bf16 ----
    float es[2];
    #pragma unroll
    for (int rt = 0; rt < 2; ++rt) {
        es[rt] = 0.f;
        #pragma unroll
        for (int nt = 0; nt < 8; ++nt) {
            f4 pv;
            #pragma unroll
            for (int r = 0; r < 4; ++r) {
                float p = __expf(-acc[rt][nt][r] * sc[rt]);
                acc[rt][nt][r] = p;
                pv[r] = p;
                es[rt] += p;
            }
            unsigned int lo = (unsigned int)f2bf(pv[0]) | ((unsigned int)f2bf(pv[1]) << 16);
            unsigned int hi = (unsigned int)f2bf(pv[2]) | ((unsigned int)f2bf(pv[3]) << 16);
            *(uint2*)(as_s + (rt * 16 + cl) * 520 + nb + nt * 16 + g * 4) =
                make_uint2(lo, hi);
        }
        es[rt] += __shfl_xor(es[rt], 16, 64);
        es[rt] += __shfl_xor(es[rt], 32, 64);
    }
    if (l < 16) {
        red_b[w * 16 + cl]      = es[0];
        red_b[64 + w * 16 + cl] = es[1];
    }
    LOADCT(ctB, 1);
    __syncthreads();                               // barrier 3 (es + as_s ready)

    float rn[2];
    #pragma unroll
    for (int rt = 0; rt < 2; ++rt) {
        rn[rt] = 1.0f / (red_b[rt * 64 + cl] + red_b[rt * 64 + 16 + cl]
                       + red_b[rt * 64 + 32 + cl] + red_b[rt * 64 + 48 + cl]);
    }

    // ---- GEMM2 with interleaved out1 stores + per-tile out2 stores ----
    {
        ffrag acc2[2][4];
        #pragma unroll
        for (int rt = 0; rt < 2; ++rt)
            #pragma unroll
            for (int nt = 0; nt < 4; ++nt) acc2[rt][nt] = fzero();

        G2COMP(ctA, 0);  LOADCT(ctA, 2);
        G2COMP(ctB, 1);  LOADCT(ctB, 3);
        G2COMP(ctA, 2);  LOADCT(ctA, 4);
        G2COMP(ctB, 3);  G2TILE(0); LOADCT(ctB, 5);
        G2COMP(ctA, 4);  LOADCT(ctA, 6);
        G2COMP(ctB, 5);  LOADCT(ctB, 7);
        G2COMP(ctA, 6);  LOADCT(ctA, 8);
        G2COMP(ctB, 7);  G2TILE(1); LOADCT(ctB, 9);
        G2COMP(ctA, 8);  LOADCT(ctA, 10);
        G2COMP(ctB, 9);  LOADCT(ctB, 11);
        G2COMP(ctA, 10); LOADCT(ctA, 12);
        G2COMP(ctB, 11); G2TILE(2); LOADCT(ctB, 13);
        G2COMP(ctA, 12); LOADCT(ctA, 14);
        G2COMP(ctB, 13); LOADCT(ctB, 15);
        G2COMP(ctA, 14);
        G2COMP(ctB, 15); G2TILE(3);
    }

#undef LOADCB
#undef G1COMP
#undef LOADCT
#undef G2COMP
#undef G2TILE
}

extern "C" void kernel_launch(void* const* d_in, const int* in_sizes, int n_in,
                              void* d_out, int out_size, void* d_ws, size_t ws_size,
                              hipStream_t stream)
{
    const float* x   = (const float*)d_in[0];
    const float* lnw = (const float*)d_in[1];
    const float* lnb = (const float*)d_in[2];
    const float* C   = (const float*)d_in[3];

    float* out0 = (float*)d_out;
    float* out1 = out0 + (size_t)M_ROWS * K_CL;
    float* out2 = out1 + (size_t)M_ROWS * K_CL;

    unsigned short* Cb = (unsigned short*)d_ws;                       // 512*256 bf16
    unsigned short* Ct = Cb + (size_t)K_CL * D_DIM;                   // 256*512 bf16
    float*          cs = (float*)((char*)d_ws + 2u * K_CL * D_DIM * 2u); // [512] f32

    prep_kernel<<<8, 256, 0, stream>>>(C, Cb, Ct, cs);
    fused_kernel<<<M_ROWS / 32, 256, 0, stream>>>(x, lnw, lnb, Cb, Ct, cs,
                                                  out0, out1, out2);
}